// Round 14
// baseline (414.753 us; speedup 1.0000x reference)
//
#include <hip/hip_runtime.h>
#include <hip/hip_bf16.h>
#include <cstdint>
#include <cstddef>

#define BB 256
#define NN 128
#define LL 2048
#define DD 64
#define KS 23
#define CPAD 12   // column pad in conv tile (band window requires 11..13)
#define EPSF 1e-6f
#define ACH 8     // attention L-chunks: block covers 256 rows
#define NCH 81    // conv W=32 K-chunks (k8 pairs over 24x56 band, i=23 zeroed)

typedef __bf16 v8bf __attribute__((ext_vector_type(8)));
typedef float v4f __attribute__((ext_vector_type(4)));
typedef float v16f __attribute__((ext_vector_type(16)));

__device__ __forceinline__ float bf2f(uint32_t u) {
  union { uint32_t i; float f; } c; c.i = u << 16; return c.f;
}
__device__ __forceinline__ uint16_t f2bf(float f) {
  union { float f; uint32_t i; } c; c.f = f;
  uint32_t i = c.i;
  return (uint16_t)((i + 0x7fffu + ((i >> 16) & 1u)) >> 16);
}
__device__ __forceinline__ v8bf cvt8(float4 f0, float4 f1) {
  v8bf r;
  r[0] = (__bf16)f0.x; r[1] = (__bf16)f0.y; r[2] = (__bf16)f0.z; r[3] = (__bf16)f0.w;
  r[4] = (__bf16)f1.x; r[5] = (__bf16)f1.y; r[6] = (__bf16)f1.z; r[7] = (__bf16)f1.w;
  return r;
}

// ----------------------------------------------------------- GNN (MFMA) ----
// 512 threads = 8 waves (2/SIMD); wave w owns rows [16w,16w+16).
// Adjacency A-frags layer-invariant: loaded once into VGPRs.
// Blocks 0..2 build the W=32 conv B-table (btab2). NO device-scope fences.
#define XSS 68    // xs row stride (words)
#define HTS3 136  // hsT row stride (halves)

__global__ __launch_bounds__(512) void gnn_kernel(
    const int* __restrict__ atoms, const float* __restrict__ atoms_mask,
    const float* __restrict__ adj, const float* __restrict__ emb_fp,
    const float* __restrict__ W_gnn, const float* __restrict__ b_gnn,
    const float* __restrict__ W_att, const float* __restrict__ b_att,
    const float* __restrict__ conv_k, uint16_t* __restrict__ btab2,
    float* __restrict__ compound, float* __restrict__ hvec_g)
{
  __shared__ float xs[NN * XSS];
  __shared__ uint16_t hsT[DD * HTS3];
  __shared__ float mask_s[NN];
  __shared__ float psum[8][64];
  __shared__ float cvec[64];

  const int b = blockIdx.x;
  const int tid = threadIdx.x;
  const int lane = tid & 63;
  const int w = tid >> 6;         // 0..7
  const int m16 = lane & 15;
  const int s = lane >> 4;

  const int row0 = 16 * w;
  v8bf adjf[4];
  {
    const float* adjw = adj + ((size_t)b * NN + row0 + m16) * NN;
    #pragma unroll
    for (int kc = 0; kc < 4; ++kc) {
      const float* p = adjw + kc * 32 + s * 8;
      adjf[kc] = cvt8(((const float4*)p)[0], ((const float4*)p)[1]);
    }
  }

  for (int idx = tid; idx < NN * 16; idx += 512) {
    int n = idx >> 4, c4 = idx & 15;
    int a = atoms[b * NN + n];
    float4 v = ((const float4*)(emb_fp + (size_t)a * DD))[c4];
    *(float4*)(xs + n * XSS + c4 * 4) = v;
  }
  if (tid < NN) mask_s[tid] = atoms_mask[b * NN + tid];
  __syncthreads();

  for (int layer = 0; layer < 3; ++layer) {
    v8bf Wf[2][4];
    float bias[4];
    const float* Wl = W_gnn + (size_t)layer * DD * DD;
    #pragma unroll
    for (int nt = 0; nt < 4; ++nt) {
      bias[nt] = b_gnn[layer * DD + nt * 16 + m16];
      #pragma unroll
      for (int kc = 0; kc < 2; ++kc) {
        const float* p = Wl + (size_t)(nt * 16 + m16) * DD + kc * 32 + s * 8;
        Wf[kc][nt] = cvt8(((const float4*)p)[0], ((const float4*)p)[1]);
      }
    }

    v4f acc[4];
    #pragma unroll
    for (int nt = 0; nt < 4; ++nt)
      acc[nt] = (v4f){bias[nt], bias[nt], bias[nt], bias[nt]};
    #pragma unroll
    for (int kc = 0; kc < 2; ++kc) {
      const float* p = xs + (size_t)(row0 + m16) * XSS + kc * 32 + s * 8;
      v8bf Axs = cvt8(((const float4*)p)[0], ((const float4*)p)[1]);
      #pragma unroll
      for (int nt = 0; nt < 4; ++nt)
        acc[nt] = __builtin_amdgcn_mfma_f32_16x16x32_bf16(
            Axs, Wf[kc][nt], acc[nt], 0, 0, 0);
    }
    __syncthreads();
    #pragma unroll
    for (int nt = 0; nt < 4; ++nt) {
      int e = nt * 16 + m16;
      int m = row0 + s * 4;
      union { uint64_t u; __bf16 h[4]; } pk;
      #pragma unroll
      for (int r = 0; r < 4; ++r)
        pk.h[r] = (__bf16)fmaxf(acc[nt][r], 0.f);
      *(uint64_t*)(hsT + (size_t)e * HTS3 + m) = pk.u;
    }
    __syncthreads();

    v4f acc2[4];
    #pragma unroll
    for (int nt = 0; nt < 4; ++nt)
      #pragma unroll
      for (int r = 0; r < 4; ++r)
        acc2[nt][r] = xs[(size_t)(row0 + s * 4 + r) * XSS + nt * 16 + m16];
    #pragma unroll
    for (int kc = 0; kc < 4; ++kc) {
      v8bf Bh[4];
      #pragma unroll
      for (int nt = 0; nt < 4; ++nt)
        Bh[nt] = *(const v8bf*)(hsT + (size_t)(nt * 16 + m16) * HTS3 + kc * 32 + s * 8);
      #pragma unroll
      for (int nt = 0; nt < 4; ++nt)
        acc2[nt] = __builtin_amdgcn_mfma_f32_16x16x32_bf16(
            adjf[kc], Bh[nt], acc2[nt], 0, 0, 0);
    }
    #pragma unroll
    for (int nt = 0; nt < 4; ++nt)
      #pragma unroll
      for (int r = 0; r < 4; ++r)
        xs[(size_t)(row0 + s * 4 + r) * XSS + nt * 16 + m16] = acc2[nt][r];
  }

  float pr = 0.f;
  for (int i = 0; i < 16; ++i) {
    int n = row0 + i;
    pr = fmaf(mask_s[n], xs[(size_t)n * XSS + lane], pr);
  }
  psum[w][lane] = pr;
  __syncthreads();
  if (tid < 64) {
    float ssum = 0.f;
    #pragma unroll
    for (int k = 0; k < 8; ++k) ssum += psum[k][tid];
    float den = 0.f;
    #pragma unroll 8
    for (int i = 0; i < NN; ++i) den += mask_s[i];
    float c = ssum / (den + EPSF);
    compound[b * DD + tid] = c;
    cvec[tid] = c;
  }
  __syncthreads();
  if (tid < 64) {
    float a = b_att[tid];
    const float* wr = W_att + (size_t)tid * DD;
    #pragma unroll
    for (int d4 = 0; d4 < 16; ++d4) {
      float4 w4 = ((const float4*)wr)[d4];
      float4 c4 = ((const float4*)cvec)[d4];
      a = fmaf(w4.x, c4.x, a); a = fmaf(w4.y, c4.y, a);
      a = fmaf(w4.z, c4.z, a); a = fmaf(w4.w, c4.w, a);
    }
    hvec_g[b * DD + tid] = fmaxf(a, 0.f);
  }

  // ---- W=32 B-table tail (blocks 0..2 only; layer = b) ----
  // B[k][n] for k = 8*k8 + j, k8 = 2kk + (lane>>5), n = lane&31:
  // value = conv_k[i, c8*8 + j - n - 1], i = k8/7, c8 = k8%7 (zero outside).
  if (b < 3) {
    const int n32 = lane & 31;
    const int sh = lane >> 5;
    for (int kk = w; kk < NCH; kk += 8) {
      int k8 = 2 * kk + sh;
      int i = k8 / 7;
      int c8v = k8 - 7 * i;
      #pragma unroll
      for (int j = 0; j < 8; ++j) {
        int jj = c8v * 8 + j - n32 - 1;
        float v = (i < KS && jj >= 0 && jj < KS)
                      ? conv_k[b * KS * KS + i * KS + jj] : 0.f;
        btab2[(((size_t)b * NCH + kk) * 64 + lane) * 8 + j] = f2bf(v);
      }
    }
  }
}

// --------------------------------------------------- conv (32x32x16 MFMA) --
// W=32 d-groups cut A-read bytes/output from 116 to 81 (vs 16x16 W=16).
// Block: 128 l-rows, 4 waves; wave = (m-half mh = g>>1) x (d-group dg = g&1),
// 2 independent 32x32 accumulators per wave (breaks the MFMA dep chain).
// B-frags: 81 chunks don't fit in VGPRs -> 3 register passes of 27 (L2-hot
// reloads, ~85 GB/s/CU < 135 ceiling). occ=2 (proven clean stores).
#define TW 88
#define TR2 150

__global__ __launch_bounds__(256, 2) void conv_kernel(
    const uint16_t* __restrict__ in, uint16_t* __restrict__ out,
    const uint16_t* __restrict__ btab2, const float* __restrict__ conv_b,
    const int* __restrict__ amino, const float* __restrict__ emb_word,
    int layer, int gmode)
{
  __shared__ uint16_t tile[TR2 * TW];   // 26400 B
  const int tid = threadIdx.x;
  const int l0 = blockIdx.x * 128;
  const int b  = blockIdx.y;
  const int lane = tid & 63;
  const int g = tid >> 6;

  // zero halo columns
  for (int i = tid; i < TR2 * 6; i += 256) {
    int r = i / 6, h = i - r * 6;
    int off = (h < 3) ? h * 4 : 76 + (h - 3) * 4;
    *(uint2*)(tile + r * TW + off) = make_uint2(0u, 0u);
  }
  // stage data cols 12..75
  const uint16_t* inb = in + (size_t)b * LL * DD;
  for (int idx = tid; idx < TR2 * 8; idx += 256) {
    int t = idx >> 3, c8 = idx & 7;
    int gl = l0 - 11 + t;
    uint16_t* dst = tile + t * TW + CPAD + c8 * 8;
    if (gl >= 0 && gl < LL) {
      if (gmode) {
        int a = amino[b * LL + gl];
        const float* src = emb_word + (size_t)a * DD + c8 * 8;
        float4 f0 = ((const float4*)src)[0];
        float4 f1 = ((const float4*)src)[1];
        union { uint2 u2[2]; uint16_t h[8]; } pk;
        pk.h[0] = f2bf(f0.x); pk.h[1] = f2bf(f0.y);
        pk.h[2] = f2bf(f0.z); pk.h[3] = f2bf(f0.w);
        pk.h[4] = f2bf(f1.x); pk.h[5] = f2bf(f1.y);
        pk.h[6] = f2bf(f1.z); pk.h[7] = f2bf(f1.w);
        *(uint2*)(dst)     = pk.u2[0];
        *(uint2*)(dst + 4) = pk.u2[1];
      } else {
        uint4 v = *(const uint4*)(inb + (size_t)gl * DD + c8 * 8);
        *(uint2*)(dst)     = make_uint2(v.x, v.y);
        *(uint2*)(dst + 4) = make_uint2(v.z, v.w);
      }
    } else {
      *(uint2*)(dst)     = make_uint2(0u, 0u);
      *(uint2*)(dst + 4) = make_uint2(0u, 0u);
    }
  }
  __syncthreads();

  const int n32 = lane & 31;
  const int sh = lane >> 5;       // k8 half
  const int dg = g & 1;           // d in [32dg, 32dg+32)
  const int mh = g >> 1;          // l-rows [64mh, 64mh+64)
  const uint16_t* bt = btab2 + (size_t)layer * NCH * 512 + lane * 8;

  v16f acc0, acc1;
  #pragma unroll
  for (int r = 0; r < 16; ++r) { acc0[r] = 0.f; acc1[r] = 0.f; }

  #pragma unroll
  for (int pass = 0; pass < 3; ++pass) {
    v8bf Bf[27];
    #pragma unroll
    for (int t = 0; t < 27; ++t)
      Bf[t] = *(const v8bf*)(bt + (size_t)(pass * 27 + t) * 512);
    #pragma unroll
    for (int t = 0; t < 27; ++t) {
      int k8 = 2 * (pass * 27 + t) + sh;
      int i = k8 / 7;
      if (i > 22) i = 22;   // k8=161 pad row: B=0, clamp keeps read in-bounds
      int c8v = k8 - 7 * ((2 * (pass * 27 + t) + sh) / 7);
      // recompute c8v with unclamped i for correct column
      c8v = (2 * (pass * 27 + t) + sh) - 7 * ((2 * (pass * 27 + t) + sh) / 7);
      const uint16_t* ap = tile + (size_t)(64 * mh + n32 + i) * TW + 32 * dg + c8v * 8;
      v8bf a0 = *(const v8bf*)(ap);
      v8bf a1 = *(const v8bf*)(ap + 32 * TW);
      acc0 = __builtin_amdgcn_mfma_f32_32x32x16_bf16(a0, Bf[t], acc0, 0, 0, 0);
      acc1 = __builtin_amdgcn_mfma_f32_32x32x16_bf16(a1, Bf[t], acc1, 0, 0, 0);
    }
  }

  // epilogue: C/D layout col = lane&31, row = (reg&3) + 8*(reg>>2) + 4*sh
  const float bias = conv_b[layer];
  uint16_t* outb = out + ((size_t)b * LL + l0 + 64 * mh) * DD + 32 * dg + n32;
  #pragma unroll
  for (int reg = 0; reg < 16; ++reg) {
    int row = (reg & 3) + 8 * (reg >> 2) + 4 * sh;
    outb[(size_t)row * DD]        = f2bf(fmaxf(acc0[reg] + bias, 0.f));
    outb[(size_t)(32 + row) * DD] = f2bf(fmaxf(acc1[reg] + bias, 0.f));
  }
}

// --------------------------------------------- attention partials (MFMA) ---
#define HTS2 66

__global__ __launch_bounds__(256) void attn_part_kernel(
    const uint16_t* __restrict__ ps, const float* __restrict__ amino_mask,
    const float* __restrict__ hvec_g, const float* __restrict__ W_att,
    const float* __restrict__ b_att, float* __restrict__ pacc_part,
    float* __restrict__ msum_part)
{
  __shared__ float ht[4][32 * HTS2];
  __shared__ float pm_s[4][64];
  __shared__ float wv_s[4][32];
  __shared__ float hv_s[64];

  const int chunk = blockIdx.x;
  const int b = blockIdx.y;
  const int tid = threadIdx.x;
  const int lane = tid & 63;
  const int w = tid >> 6;
  const int m16 = lane & 15;
  const int s = lane >> 4;

  v8bf bfrB[2][4];
  float bias[4];
  #pragma unroll
  for (int nt = 0; nt < 4; ++nt) {
    bias[nt] = b_att[nt * 16 + m16];
    const float* wr = W_att + (size_t)(nt * 16 + m16) * DD + s * 8;
    #pragma unroll
    for (int kc = 0; kc < 2; ++kc) {
      float4 f0 = ((const float4*)(wr + kc * 32))[0];
      float4 f1 = ((const float4*)(wr + kc * 32))[1];
      bfrB[kc][nt] = cvt8(f0, f1);
    }
  }
  if (tid < 64) hv_s[tid] = hvec_g[b * DD + tid];

  const int rowbase = chunk * 256 + w * 64;
  const float* pmb = amino_mask + (size_t)b * LL;
  pm_s[w][lane] = pmb[rowbase + lane];
  const float macc = pm_s[w][lane];
  __syncthreads();

  float pacc[4] = {0.f, 0.f, 0.f, 0.f};
  const uint16_t* psb = ps + ((size_t)b * LL + rowbase) * DD;

  #pragma unroll
  for (int step = 0; step < 2; ++step) {
    const uint16_t* pr = psb + (size_t)step * 32 * DD;
    v8bf A[2][2];
    #pragma unroll
    for (int mt = 0; mt < 2; ++mt)
      #pragma unroll
      for (int kc = 0; kc < 2; ++kc)
        A[mt][kc] = *(const v8bf*)(pr + (mt * 16 + m16) * DD + kc * 32 + s * 8);

    v4f acc[2][4];
    #pragma unroll
    for (int mt = 0; mt < 2; ++mt)
      #pragma unroll
      for (int nt = 0; nt < 4; ++nt)
        acc[mt][nt] = (v4f){0.f, 0.f, 0.f, 0.f};
    #pragma unroll
    for (int kc = 0; kc < 2; ++kc)
      #pragma unroll
      for (int mt = 0; mt < 2; ++mt)
        #pragma unroll
        for (int nt = 0; nt < 4; ++nt)
          acc[mt][nt] = __builtin_amdgcn_mfma_f32_16x16x32_bf16(
              A[mt][kc], bfrB[kc][nt], acc[mt][nt], 0, 0, 0);

    float vals[2][4][4];
    float* htw = ht[w];
    #pragma unroll
    for (int mt = 0; mt < 2; ++mt)
      #pragma unroll
      for (int r = 0; r < 4; ++r) {
        int row = mt * 16 + s * 4 + r;
        float pm = pm_s[w][step * 32 + row];
        #pragma unroll
        for (int nt = 0; nt < 4; ++nt) {
          float v = fmaxf(acc[mt][nt][r] + bias[nt], 0.f) * pm;
          vals[mt][nt][r] = v;
          htw[row * HTS2 + nt * 16 + m16] = v;
        }
      }
    __syncthreads();

    {
      int row = lane & 31, eh = lane >> 5;
      const float* hr = ht[w] + row * HTS2 + eh * 32;
      const float* hv = hv_s + eh * 32;
      float d = 0.f;
      #pragma unroll
      for (int t = 0; t < 8; ++t) {
        float4 hh = *(const float4*)(hr + 4 * t);
        float4 vv = *(const float4*)(hv + 4 * t);
        d = fmaf(hh.x, vv.x, d); d = fmaf(hh.y, vv.y, d);
        d = fmaf(hh.z, vv.z, d); d = fmaf(hh.w, vv.w, d);
      }
      d += __shfl_xor(d, 32);
      float wt = tanhf(d);
      if (lane < 32) wv_s[w][row] = wt;
    }
    __syncthreads();

    #pragma unroll
    for (int mt = 0; mt < 2; ++mt)
      #pragma unroll
      for (int r = 0; r < 4; ++r) {
        float wt = wv_s[w][mt * 16 + s * 4 + r];
        #pragma unroll
        for (int nt = 0; nt < 4; ++nt)
          pacc[nt] = fmaf(wt, vals[mt][nt][r], pacc[nt]);
      }
    __syncthreads();
  }

  const size_t idx = ((size_t)b * ACH + chunk) * 4 + w;
  #pragma unroll
  for (int nt = 0; nt < 4; ++nt) {
    float p = pacc[nt];
    p += __shfl_xor(p, 16);
    p += __shfl_xor(p, 32);
    if (m16 == lane)
      pacc_part[idx * 64 + nt * 16 + lane] = p;
  }
  float m = macc;
  #pragma unroll
  for (int off = 1; off < 64; off <<= 1) m += __shfl_xor(m, off);
  if (lane == 0) msum_part[idx] = m;
}

// --------------------------------------------------- finalize + FC head ----
__global__ __launch_bounds__(128) void attn_final_kernel(
    const float* __restrict__ compound, const float* __restrict__ pacc_part,
    const float* __restrict__ msum_part, const float* __restrict__ W_out,
    const float* __restrict__ b_out, const float* __restrict__ W_int,
    const float* __restrict__ b_int, float* __restrict__ outp)
{
  __shared__ float cat[128];
  __shared__ float cat2[128];
  const int b = blockIdx.x;
  const int tid = threadIdx.x;

  if (tid < 64) {
    float p = 0.f, den = 0.f;
    #pragma unroll 4
    for (int c = 0; c < ACH * 4; ++c) {
      p += pacc_part[((size_t)b * ACH * 4 + c) * 64 + tid];
      den += msum_part[b * ACH * 4 + c];
    }
    cat[tid] = compound[b * DD + tid];
    cat[64 + tid] = p / (den + EPSF);
  }
  __syncthreads();
  {
    float a = b_out[tid];
    const float* wr = W_out + (size_t)tid * 128;
    #pragma unroll 8
    for (int dd = 0; dd < 128; ++dd) a = fmaf(wr[dd], cat[dd], a);
    cat2[tid] = fmaxf(a, 0.f);
  }
  __syncthreads();
  {
    float a = b_out[128 + tid];
    const float* wr = W_out + 128 * 128 + (size_t)tid * 128;
    #pragma unroll 8
    for (int dd = 0; dd < 128; ++dd) a = fmaf(wr[dd], cat2[dd], a);
    __syncthreads();
    cat[tid] = fmaxf(a, 0.f);
  }
  __syncthreads();
  if (tid < 2) {
    float a = b_int[tid];
    const float* wr = W_int + (size_t)tid * 128;
    #pragma unroll 8
    for (int dd = 0; dd < 128; ++dd) a = fmaf(wr[dd], cat[dd], a);
    outp[b * 2 + tid] = a;
  }
}

// -------------------------------------------------------------- launch -----
extern "C" void kernel_launch(void* const* d_in, const int* in_sizes, int n_in,
                              void* d_out, int out_size, void* d_ws, size_t ws_size,
                              hipStream_t stream) {
  const int*   atoms      = (const int*)d_in[0];
  const float* atoms_mask = (const float*)d_in[1];
  const float* adjacency  = (const float*)d_in[2];
  const int*   amino      = (const int*)d_in[3];
  const float* amino_mask = (const float*)d_in[4];
  const float* emb_fp     = (const float*)d_in[5];
  const float* emb_word   = (const float*)d_in[6];
  const float* W_gnn      = (const float*)d_in[7];
  const float* b_gnn      = (const float*)d_in[8];
  const float* conv_k     = (const float*)d_in[9];
  const float* conv_b     = (const float*)d_in[10];
  const float* W_att      = (const float*)d_in[11];
  const float* b_att      = (const float*)d_in[12];
  const float* W_out      = (const float*)d_in[13];
  const float* b_out      = (const float*)d_in[14];
  const float* W_int      = (const float*)d_in[15];
  const float* b_int      = (const float*)d_in[16];
  float* out = (float*)d_out;

  char* ws = (char*)d_ws;
  const size_t ps_bytes = (size_t)BB * LL * DD * 2;   // 64 MB each
  float*    compound  = (float*)ws;                                   // 64 KB
  uint16_t* ps_a      = (uint16_t*)(ws + 65536);
  uint16_t* ps_b      = (uint16_t*)(ws + 65536 + ps_bytes);
  uint16_t* btab2     = (uint16_t*)(ws + 65536 + 2 * ps_bytes);       // 249 KB
  float*    hvec_g    = (float*)(ws + 65536 + 2 * ps_bytes + 262144); // 64 KB
  // attn partials alias ps_a: ps_a's last reader is conv2; attn_part (sole
  // writer of these) is ordered after conv2.
  float*    pacc_part = (float*)ps_a;
  float*    msum_part = (float*)((char*)ps_a + (size_t)BB * ACH * 4 * 64 * 4);

  // gnn (+W=32 B-table tail in blocks 0..2)
  gnn_kernel<<<BB, 512, 0, stream>>>(atoms, atoms_mask, adjacency, emb_fp,
                                     W_gnn, b_gnn, W_att, b_att,
                                     conv_k, btab2, compound, hvec_g);
  // conv0 gathers emb_word[amino] in staging (gmode=1); 128-row blocks
  conv_kernel<<<dim3(16, BB), 256, 0, stream>>>(ps_a, ps_b, btab2, conv_b,
                                                amino, emb_word, 0, 1);
  conv_kernel<<<dim3(16, BB), 256, 0, stream>>>(ps_b, ps_a, btab2, conv_b,
                                                amino, emb_word, 1, 0);
  conv_kernel<<<dim3(16, BB), 256, 0, stream>>>(ps_a, ps_b, btab2, conv_b,
                                                amino, emb_word, 2, 0);
  attn_part_kernel<<<dim3(ACH, BB), 256, 0, stream>>>(ps_b, amino_mask, hvec_g,
                                                      W_att, b_att,
                                                      pacc_part, msum_part);
  attn_final_kernel<<<BB, 128, 0, stream>>>(compound, pacc_part, msum_part,
                                            W_out, b_out, W_int, b_int, out);
}

// Round 15
// 370.471 us; speedup vs baseline: 1.1195x; 1.1195x over previous
//
#include <hip/hip_runtime.h>
#include <hip/hip_bf16.h>
#include <cstdint>
#include <cstddef>

#define BB 256
#define NN 128
#define LL 2048
#define DD 64
#define KS 23
#define CPAD 12   // column pad in conv tile (band window requires 11..13)
#define EPSF 1e-6f
#define ACH 8     // attention L-chunks: block covers 256 rows

typedef __bf16 v8bf __attribute__((ext_vector_type(8)));
typedef float v4f __attribute__((ext_vector_type(4)));

__device__ __forceinline__ float bf2f(uint32_t u) {
  union { uint32_t i; float f; } c; c.i = u << 16; return c.f;
}
__device__ __forceinline__ uint16_t f2bf(float f) {
  union { float f; uint32_t i; } c; c.f = f;
  uint32_t i = c.i;
  return (uint16_t)((i + 0x7fffu + ((i >> 16) & 1u)) >> 16);
}
__device__ __forceinline__ v8bf cvt8(float4 f0, float4 f1) {
  v8bf r;
  r[0] = (__bf16)f0.x; r[1] = (__bf16)f0.y; r[2] = (__bf16)f0.z; r[3] = (__bf16)f0.w;
  r[4] = (__bf16)f1.x; r[5] = (__bf16)f1.y; r[6] = (__bf16)f1.z; r[7] = (__bf16)f1.w;
  return r;
}

// ----------------------------------------------------------- GNN (MFMA) ----
// 512 threads = 8 waves (2/SIMD); wave w owns rows [16w,16w+16).
// Adjacency A-frags layer-invariant: loaded once into VGPRs (r13).
// Blocks 0..2 build the W=16 conv B-table. NO device-scope fences (r11).
#define XSS 68    // xs row stride (words)
#define HTS3 136  // hsT row stride (halves)

__global__ __launch_bounds__(512) void gnn_kernel(
    const int* __restrict__ atoms, const float* __restrict__ atoms_mask,
    const float* __restrict__ adj, const float* __restrict__ emb_fp,
    const float* __restrict__ W_gnn, const float* __restrict__ b_gnn,
    const float* __restrict__ W_att, const float* __restrict__ b_att,
    const float* __restrict__ conv_k, uint16_t* __restrict__ btab,
    float* __restrict__ compound, float* __restrict__ hvec_g)
{
  __shared__ float xs[NN * XSS];
  __shared__ uint16_t hsT[DD * HTS3];
  __shared__ float mask_s[NN];
  __shared__ float psum[8][64];
  __shared__ float cvec[64];

  const int b = blockIdx.x;
  const int tid = threadIdx.x;
  const int lane = tid & 63;
  const int w = tid >> 6;         // 0..7
  const int m16 = lane & 15;
  const int s = lane >> 4;

  const int row0 = 16 * w;
  v8bf adjf[4];
  {
    const float* adjw = adj + ((size_t)b * NN + row0 + m16) * NN;
    #pragma unroll
    for (int kc = 0; kc < 4; ++kc) {
      const float* p = adjw + kc * 32 + s * 8;
      adjf[kc] = cvt8(((const float4*)p)[0], ((const float4*)p)[1]);
    }
  }

  for (int idx = tid; idx < NN * 16; idx += 512) {
    int n = idx >> 4, c4 = idx & 15;
    int a = atoms[b * NN + n];
    float4 v = ((const float4*)(emb_fp + (size_t)a * DD))[c4];
    *(float4*)(xs + n * XSS + c4 * 4) = v;
  }
  if (tid < NN) mask_s[tid] = atoms_mask[b * NN + tid];
  __syncthreads();

  for (int layer = 0; layer < 3; ++layer) {
    v8bf Wf[2][4];
    float bias[4];
    const float* Wl = W_gnn + (size_t)layer * DD * DD;
    #pragma unroll
    for (int nt = 0; nt < 4; ++nt) {
      bias[nt] = b_gnn[layer * DD + nt * 16 + m16];
      #pragma unroll
      for (int kc = 0; kc < 2; ++kc) {
        const float* p = Wl + (size_t)(nt * 16 + m16) * DD + kc * 32 + s * 8;
        Wf[kc][nt] = cvt8(((const float4*)p)[0], ((const float4*)p)[1]);
      }
    }

    // hs GEMM: M=16, N=64 (4 nt), K=64 (2 kc)
    v4f acc[4];
    #pragma unroll
    for (int nt = 0; nt < 4; ++nt)
      acc[nt] = (v4f){bias[nt], bias[nt], bias[nt], bias[nt]};
    #pragma unroll
    for (int kc = 0; kc < 2; ++kc) {
      const float* p = xs + (size_t)(row0 + m16) * XSS + kc * 32 + s * 8;
      v8bf Axs = cvt8(((const float4*)p)[0], ((const float4*)p)[1]);
      #pragma unroll
      for (int nt = 0; nt < 4; ++nt)
        acc[nt] = __builtin_amdgcn_mfma_f32_16x16x32_bf16(
            Axs, Wf[kc][nt], acc[nt], 0, 0, 0);
    }
    __syncthreads();   // WAR on hsT
    #pragma unroll
    for (int nt = 0; nt < 4; ++nt) {
      int e = nt * 16 + m16;
      int m = row0 + s * 4;
      union { uint64_t u; __bf16 h[4]; } pk;
      #pragma unroll
      for (int r = 0; r < 4; ++r)
        pk.h[r] = (__bf16)fmaxf(acc[nt][r], 0.f);
      *(uint64_t*)(hsT + (size_t)e * HTS3 + m) = pk.u;
    }
    __syncthreads();   // RAW on hsT

    // adj GEMM: M=16, N=64, K=128 (4 kc); C init = old xs
    v4f acc2[4];
    #pragma unroll
    for (int nt = 0; nt < 4; ++nt)
      #pragma unroll
      for (int r = 0; r < 4; ++r)
        acc2[nt][r] = xs[(size_t)(row0 + s * 4 + r) * XSS + nt * 16 + m16];
    #pragma unroll
    for (int kc = 0; kc < 4; ++kc) {
      v8bf Bh[4];
      #pragma unroll
      for (int nt = 0; nt < 4; ++nt)
        Bh[nt] = *(const v8bf*)(hsT + (size_t)(nt * 16 + m16) * HTS3 + kc * 32 + s * 8);
      #pragma unroll
      for (int nt = 0; nt < 4; ++nt)
        acc2[nt] = __builtin_amdgcn_mfma_f32_16x16x32_bf16(
            adjf[kc], Bh[nt], acc2[nt], 0, 0, 0);
    }
    #pragma unroll
    for (int nt = 0; nt < 4; ++nt)
      #pragma unroll
      for (int r = 0; r < 4; ++r)
        xs[(size_t)(row0 + s * 4 + r) * XSS + nt * 16 + m16] = acc2[nt][r];
  }

  float pr = 0.f;
  for (int i = 0; i < 16; ++i) {
    int n = row0 + i;
    pr = fmaf(mask_s[n], xs[(size_t)n * XSS + lane], pr);
  }
  psum[w][lane] = pr;
  __syncthreads();
  if (tid < 64) {
    float ssum = 0.f;
    #pragma unroll
    for (int k = 0; k < 8; ++k) ssum += psum[k][tid];
    float den = 0.f;
    #pragma unroll 8
    for (int i = 0; i < NN; ++i) den += mask_s[i];
    float c = ssum / (den + EPSF);
    compound[b * DD + tid] = c;
    cvec[tid] = c;
  }
  __syncthreads();
  if (tid < 64) {
    float a = b_att[tid];
    const float* wr = W_att + (size_t)tid * DD;
    #pragma unroll
    for (int d4 = 0; d4 < 16; ++d4) {
      float4 w4 = ((const float4*)wr)[d4];
      float4 c4 = ((const float4*)cvec)[d4];
      a = fmaf(w4.x, c4.x, a); a = fmaf(w4.y, c4.y, a);
      a = fmaf(w4.z, c4.z, a); a = fmaf(w4.w, c4.w, a);
    }
    hvec_g[b * DD + tid] = fmaxf(a, 0.f);
  }

  // ---- bfrag tail (blocks 0..2 only; layer = b) ----
  if (b < 3) {
    for (int kk = w; kk < 30; kk += 8) {
      int k8 = kk * 4 + s;
      int i = k8 / 5;
      int c8k = k8 - i * 5;
      #pragma unroll
      for (int j = 0; j < 8; ++j) {
        int c = c8k * 8 + j;
        int jj = c - m16 - 1;
        float v = (i < KS && jj >= 0 && jj < KS)
                      ? conv_k[b * KS * KS + i * KS + jj] : 0.f;
        btab[(((size_t)b * 30 + kk) * 64 + lane) * 8 + j] = f2bf(v);
      }
    }
  }
}

// --------------------------------------------------------------- conv ------
// Round-12 champion, restored. Two-sided floor at ~89 us (r14: the W=32
// variant trades LDS reads for global B-streaming and lands at 93 us —
// VGPR cap evicts the bigger B-table). occ=2 (occ>2 neutral: LDS pipe
// saturated; occ4 + 2B stores explodes HBM writes). kk<29: chunk 29 is the
// all-zero i=23 pad row. SQ_LDS_BANK_CONFLICT ~1.5e7 here is intrinsic
// b128 multi-cycle counting, not fixable conflicts (r13 parity-swap no-op).
// gmode=1: staging gathers emb_word[amino] (layer 0).
#define TW 88
#define TROWS 86

__global__ __launch_bounds__(256, 2) void conv_kernel(
    const uint16_t* __restrict__ in, uint16_t* __restrict__ out,
    const uint16_t* __restrict__ btab, const float* __restrict__ conv_b,
    const int* __restrict__ amino, const float* __restrict__ emb_word,
    int layer, int gmode)
{
  __shared__ uint16_t tile[TROWS * TW];
  const int tid = threadIdx.x;
  const int l0 = blockIdx.x * 64;
  const int b  = blockIdx.y;
  const int lane = tid & 63;
  const int g = tid >> 6;

  v8bf bfr[29];
  const uint16_t* bt = btab + (size_t)layer * 30 * 512 + lane * 8;
  #pragma unroll
  for (int kk = 0; kk < 29; ++kk)
    bfr[kk] = *(const v8bf*)(bt + kk * 512);

  for (int i = tid; i < TROWS * 6; i += 256) {
    int r = i / 6, h = i - r * 6;
    int off = (h < 3) ? h * 4 : 76 + (h - 3) * 4;
    *(uint2*)(tile + r * TW + off) = make_uint2(0u, 0u);
  }
  const uint16_t* inb = in + (size_t)b * LL * DD;
  for (int idx = tid; idx < TROWS * 8; idx += 256) {
    int t = idx >> 3, c8 = idx & 7;
    int gl = l0 - 11 + t;
    uint16_t* dst = tile + t * TW + CPAD + c8 * 8;
    if (gl >= 0 && gl < LL) {
      if (gmode) {
        int a = amino[b * LL + gl];
        const float* src = emb_word + (size_t)a * DD + c8 * 8;
        float4 f0 = ((const float4*)src)[0];
        float4 f1 = ((const float4*)src)[1];
        union { uint2 u2[2]; uint16_t h[8]; } pk;
        pk.h[0] = f2bf(f0.x); pk.h[1] = f2bf(f0.y);
        pk.h[2] = f2bf(f0.z); pk.h[3] = f2bf(f0.w);
        pk.h[4] = f2bf(f1.x); pk.h[5] = f2bf(f1.y);
        pk.h[6] = f2bf(f1.z); pk.h[7] = f2bf(f1.w);
        *(uint2*)(dst)     = pk.u2[0];
        *(uint2*)(dst + 4) = pk.u2[1];
      } else {
        uint4 v = *(const uint4*)(inb + (size_t)gl * DD + c8 * 8);
        *(uint2*)(dst)     = make_uint2(v.x, v.y);
        *(uint2*)(dst + 4) = make_uint2(v.z, v.w);
      }
    } else {
      *(uint2*)(dst)     = make_uint2(0u, 0u);
      *(uint2*)(dst + 4) = make_uint2(0u, 0u);
    }
  }
  __syncthreads();

  const int s = lane >> 4;
  const int m16 = lane & 15;
  v4f acc[4];
  #pragma unroll
  for (int m = 0; m < 4; ++m) acc[m] = (v4f){0.f, 0.f, 0.f, 0.f};

  #pragma unroll
  for (int kk = 0; kk < 29; ++kk) {
    int k8 = kk * 4 + s;
    int i = k8 / 5;
    int c8 = k8 - i * 5;
    const uint16_t* ap = tile + (m16 + i) * TW + 16 * g + c8 * 8;
    v8bf a0 = *(const v8bf*)(ap);
    v8bf a1 = *(const v8bf*)(ap + 16 * TW);
    v8bf a2 = *(const v8bf*)(ap + 32 * TW);
    v8bf a3 = *(const v8bf*)(ap + 48 * TW);
    acc[0] = __builtin_amdgcn_mfma_f32_16x16x32_bf16(a0, bfr[kk], acc[0], 0, 0, 0);
    acc[1] = __builtin_amdgcn_mfma_f32_16x16x32_bf16(a1, bfr[kk], acc[1], 0, 0, 0);
    acc[2] = __builtin_amdgcn_mfma_f32_16x16x32_bf16(a2, bfr[kk], acc[2], 0, 0, 0);
    acc[3] = __builtin_amdgcn_mfma_f32_16x16x32_bf16(a3, bfr[kk], acc[3], 0, 0, 0);
  }

  const float bias = conv_b[layer];
  uint16_t* outb = out + ((size_t)b * LL + l0) * DD + 16 * g + m16;
  #pragma unroll
  for (int m = 0; m < 4; ++m) {
    #pragma unroll
    for (int r = 0; r < 4; ++r) {
      int row = m * 16 + s * 4 + r;
      outb[(size_t)row * DD] = f2bf(fmaxf(acc[m][r] + bias, 0.f));
    }
  }
}

// --------------------------------------------- attention partials (MFMA) ---
// Plain stores to per-(b,chunk,wave) slots — no atomics/fences (round 11).
#define HTS2 66

__global__ __launch_bounds__(256) void attn_part_kernel(
    const uint16_t* __restrict__ ps, const float* __restrict__ amino_mask,
    const float* __restrict__ hvec_g, const float* __restrict__ W_att,
    const float* __restrict__ b_att, float* __restrict__ pacc_part,
    float* __restrict__ msum_part)
{
  __shared__ float ht[4][32 * HTS2];
  __shared__ float pm_s[4][64];
  __shared__ float wv_s[4][32];
  __shared__ float hv_s[64];

  const int chunk = blockIdx.x;
  const int b = blockIdx.y;
  const int tid = threadIdx.x;
  const int lane = tid & 63;
  const int w = tid >> 6;
  const int m16 = lane & 15;
  const int s = lane >> 4;

  v8bf bfrB[2][4];
  float bias[4];
  #pragma unroll
  for (int nt = 0; nt < 4; ++nt) {
    bias[nt] = b_att[nt * 16 + m16];
    const float* wr = W_att + (size_t)(nt * 16 + m16) * DD + s * 8;
    #pragma unroll
    for (int kc = 0; kc < 2; ++kc) {
      float4 f0 = ((const float4*)(wr + kc * 32))[0];
      float4 f1 = ((const float4*)(wr + kc * 32))[1];
      bfrB[kc][nt] = cvt8(f0, f1);
    }
  }
  if (tid < 64) hv_s[tid] = hvec_g[b * DD + tid];

  const int rowbase = chunk * 256 + w * 64;
  const float* pmb = amino_mask + (size_t)b * LL;
  pm_s[w][lane] = pmb[rowbase + lane];
  const float macc = pm_s[w][lane];
  __syncthreads();

  float pacc[4] = {0.f, 0.f, 0.f, 0.f};
  const uint16_t* psb = ps + ((size_t)b * LL + rowbase) * DD;

  #pragma unroll
  for (int step = 0; step < 2; ++step) {
    const uint16_t* pr = psb + (size_t)step * 32 * DD;
    v8bf A[2][2];
    #pragma unroll
    for (int mt = 0; mt < 2; ++mt)
      #pragma unroll
      for (int kc = 0; kc < 2; ++kc)
        A[mt][kc] = *(const v8bf*)(pr + (mt * 16 + m16) * DD + kc * 32 + s * 8);

    v4f acc[2][4];
    #pragma unroll
    for (int mt = 0; mt < 2; ++mt)
      #pragma unroll
      for (int nt = 0; nt < 4; ++nt)
        acc[mt][nt] = (v4f){0.f, 0.f, 0.f, 0.f};
    #pragma unroll
    for (int kc = 0; kc < 2; ++kc)
      #pragma unroll
      for (int mt = 0; mt < 2; ++mt)
        #pragma unroll
        for (int nt = 0; nt < 4; ++nt)
          acc[mt][nt] = __builtin_amdgcn_mfma_f32_16x16x32_bf16(
              A[mt][kc], bfrB[kc][nt], acc[mt][nt], 0, 0, 0);

    float vals[2][4][4];
    float* htw = ht[w];
    #pragma unroll
    for (int mt = 0; mt < 2; ++mt)
      #pragma unroll
      for (int r = 0; r < 4; ++r) {
        int row = mt * 16 + s * 4 + r;
        float pm = pm_s[w][step * 32 + row];
        #pragma unroll
        for (int nt = 0; nt < 4; ++nt) {
          float v = fmaxf(acc[mt][nt][r] + bias[nt], 0.f) * pm;
          vals[mt][nt][r] = v;
          htw[row * HTS2 + nt * 16 + m16] = v;
        }
      }
    __syncthreads();

    {
      int row = lane & 31, eh = lane >> 5;
      const float* hr = ht[w] + row * HTS2 + eh * 32;
      const float* hv = hv_s + eh * 32;
      float d = 0.f;
      #pragma unroll
      for (int t = 0; t < 8; ++t) {
        float4 hh = *(const float4*)(hr + 4 * t);
        float4 vv = *(const float4*)(hv + 4 * t);
        d = fmaf(hh.x, vv.x, d); d = fmaf(hh.y, vv.y, d);
        d = fmaf(hh.z, vv.z, d); d = fmaf(hh.w, vv.w, d);
      }
      d += __shfl_xor(d, 32);
      float wt = tanhf(d);
      if (lane < 32) wv_s[w][row] = wt;
    }
    __syncthreads();

    #pragma unroll
    for (int mt = 0; mt < 2; ++mt)
      #pragma unroll
      for (int r = 0; r < 4; ++r) {
        float wt = wv_s[w][mt * 16 + s * 4 + r];
        #pragma unroll
        for (int nt = 0; nt < 4; ++nt)
          pacc[nt] = fmaf(wt, vals[mt][nt][r], pacc[nt]);
      }
    __syncthreads();
  }

  const size_t idx = ((size_t)b * ACH + chunk) * 4 + w;
  #pragma unroll
  for (int nt = 0; nt < 4; ++nt) {
    float p = pacc[nt];
    p += __shfl_xor(p, 16);
    p += __shfl_xor(p, 32);
    if (m16 == lane)
      pacc_part[idx * 64 + nt * 16 + lane] = p;
  }
  float m = macc;
  #pragma unroll
  for (int off = 1; off < 64; off <<= 1) m += __shfl_xor(m, off);
  if (lane == 0) msum_part[idx] = m;
}

// --------------------------------------------------- finalize + FC head ----
__global__ __launch_bounds__(128) void attn_final_kernel(
    const float* __restrict__ compound, const float* __restrict__ pacc_part,
    const float* __restrict__ msum_part, const float* __restrict__ W_out,
    const float* __restrict__ b_out, const float* __restrict__ W_int,
    const float* __restrict__ b_int, float* __restrict__ outp)
{
  __shared__ float cat[128];
  __shared__ float cat2[128];
  const int b = blockIdx.x;
  const int tid = threadIdx.x;

  if (tid < 64) {
    float p = 0.f, den = 0.f;
    #pragma unroll 4
    for (int c = 0; c < ACH * 4; ++c) {
      p += pacc_part[((size_t)b * ACH * 4 + c) * 64 + tid];
      den += msum_part[b * ACH * 4 + c];
    }
    cat[tid] = compound[b * DD + tid];
    cat[64 + tid] = p / (den + EPSF);
  }
  __syncthreads();
  {
    float a = b_out[tid];
    const float* wr = W_out + (size_t)tid * 128;
    #pragma unroll 8
    for (int dd = 0; dd < 128; ++dd) a = fmaf(wr[dd], cat[dd], a);
    cat2[tid] = fmaxf(a, 0.f);
  }
  __syncthreads();
  {
    float a = b_out[128 + tid];
    const float* wr = W_out + 128 * 128 + (size_t)tid * 128;
    #pragma unroll 8
    for (int dd = 0; dd < 128; ++dd) a = fmaf(wr[dd], cat2[dd], a);
    __syncthreads();
    cat[tid] = fmaxf(a, 0.f);
  }
  __syncthreads();
  if (tid < 2) {
    float a = b_int[tid];
    const float* wr = W_int + (size_t)tid * 128;
    #pragma unroll 8
    for (int dd = 0; dd < 128; ++dd) a = fmaf(wr[dd], cat[dd], a);
    outp[b * 2 + tid] = a;
  }
}

// -------------------------------------------------------------- launch -----
extern "C" void kernel_launch(void* const* d_in, const int* in_sizes, int n_in,
                              void* d_out, int out_size, void* d_ws, size_t ws_size,
                              hipStream_t stream) {
  const int*   atoms      = (const int*)d_in[0];
  const float* atoms_mask = (const float*)d_in[1];
  const float* adjacency  = (const float*)d_in[2];
  const int*   amino      = (const int*)d_in[3];
  const float* amino_mask = (const float*)d_in[4];
  const float* emb_fp     = (const float*)d_in[5];
  const float* emb_word   = (const float*)d_in[6];
  const float* W_gnn      = (const float*)d_in[7];
  const float* b_gnn      = (const float*)d_in[8];
  const float* conv_k     = (const float*)d_in[9];
  const float* conv_b     = (const float*)d_in[10];
  const float* W_att      = (const float*)d_in[11];
  const float* b_att      = (const float*)d_in[12];
  const float* W_out      = (const float*)d_in[13];
  const float* b_out      = (const float*)d_in[14];
  const float* W_int      = (const float*)d_in[15];
  const float* b_int      = (const float*)d_in[16];
  float* out = (float*)d_out;

  char* ws = (char*)d_ws;
  const size_t ps_bytes = (size_t)BB * LL * DD * 2;   // 64 MB each
  float*    compound  = (float*)ws;                                   // 64 KB
  uint16_t* ps_a      = (uint16_t*)(ws + 65536);
  uint16_t* ps_b      = (uint16_t*)(ws + 65536 + ps_bytes);
  uint16_t* btab      = (uint16_t*)(ws + 65536 + 2 * ps_bytes);       // 90 KB
  float*    hvec_g    = (float*)(ws + 65536 + 2 * ps_bytes + 131072); // 64 KB
  // attn partials alias ps_a: ps_a's last reader is conv2; attn_part (sole
  // writer of these) is ordered after conv2.
  float*    pacc_part = (float*)ps_a;
  float*    msum_part = (float*)((char*)ps_a + (size_t)BB * ACH * 4 * 64 * 4);

  // gnn (+bfrag tail in blocks 0..2)
  gnn_kernel<<<BB, 512, 0, stream>>>(atoms, atoms_mask, adjacency, emb_fp,
                                     W_gnn, b_gnn, W_att, b_att,
                                     conv_k, btab, compound, hvec_g);
  // conv0 gathers emb_word[amino] in staging (gmode=1)
  conv_kernel<<<dim3(32, BB), 256, 0, stream>>>(ps_a, ps_b, btab, conv_b,
                                                amino, emb_word, 0, 1);
  conv_kernel<<<dim3(32, BB), 256, 0, stream>>>(ps_b, ps_a, btab, conv_b,
                                                amino, emb_word, 1, 0);
  conv_kernel<<<dim3(32, BB), 256, 0, stream>>>(ps_a, ps_b, btab, conv_b,
                                                amino, emb_word, 2, 0);
  attn_part_kernel<<<dim3(ACH, BB), 256, 0, stream>>>(ps_b, amino_mask, hvec_g,
                                                      W_att, b_att,
                                                      pacc_part, msum_part);
  attn_final_kernel<<<BB, 128, 0, stream>>>(compound, pacc_part, msum_part,
                                            W_out, b_out, W_int, b_int, out);
}